// Round 13
// baseline (993.420 us; speedup 1.0000x reference)
//
#include <hip/hip_runtime.h>
#include <hip/hip_bf16.h>
#include <math.h>

#define L_SEQ 4096
#define DMODEL 1024
#define NHEAD 16
#define HDIM 64
#define NEXP 8
#define NHID 4096
#define NSLOT (L_SEQ * 2)

typedef __attribute__((ext_vector_type(4))) float f32x4;
typedef __attribute__((ext_vector_type(16))) float f32x16;
typedef __attribute__((ext_vector_type(8))) short s16x8;
typedef __attribute__((ext_vector_type(4))) short s16x4;
typedef __attribute__((ext_vector_type(4))) unsigned u32x4;

__device__ __forceinline__ short f2bf(float f) {
  __hip_bfloat16 h = __float2bfloat16(f);
  return *reinterpret_cast<short*>(&h);
}
__device__ __forceinline__ float bf2f(short s) {
  __hip_bfloat16 h;
  *reinterpret_cast<short*>(&h) = s;
  return __bfloat162float(h);
}
__device__ __forceinline__ void split3(float a, short& h, short& m, short& l) {
  h = f2bf(a);
  float r = a - bf2f(h);
  m = f2bf(r);
  float r2 = r - bf2f(m);
  l = f2bf(r2);
}
__device__ __forceinline__ void gload16(const void* g, void* l) {
  __builtin_amdgcn_global_load_lds(
      (const __attribute__((address_space(1))) void*)g,
      (__attribute__((address_space(3))) void*)l, 16, 0, 0);
}

// ---------- fused pre-pass ----------
// blocks 0..2047: split Q | 2048..4095: split K | 4096..5119: V transpose-split
// blocks 5120..21503: weight transpose (idx>>10 = z role: z<8 -> W1, else W2)
__global__ __launch_bounds__(256) void prep_kernel(
    const float* __restrict__ Q, const float* __restrict__ K, const float* __restrict__ V,
    const float* __restrict__ W1, const float* __restrict__ W2,
    short* __restrict__ Qh, short* __restrict__ Qm, short* __restrict__ Ql,
    short* __restrict__ Kh, short* __restrict__ Km, short* __restrict__ Kl,
    short* __restrict__ Vth, short* __restrict__ Vtm, short* __restrict__ Vtl,
    short* __restrict__ W1t, short* __restrict__ W2t) {
  __shared__ float T[64][65];
  const int b = blockIdx.x;
  const int t = threadIdx.x;
  if (b < 4096) {
    const bool isQ = (b < 2048);
    const float* src = isQ ? Q : K;
    short* hs = isQ ? Qh : Kh;
    short* ms = isQ ? Qm : Km;
    short* ls = isQ ? Ql : Kl;
    const float scale = isQ ? 0.125f : 1.0f;
    const int nquad = (int)((size_t)L_SEQ * DMODEL / 4);
    int i = (b & 2047) * 256 + t;
    for (; i < nquad; i += 2048 * 256) {
      f32x4 a = reinterpret_cast<const f32x4*>(src)[i];
      a *= scale;
      s16x4 h4, m4, l4;
      #pragma unroll
      for (int j = 0; j < 4; ++j) {
        short h, m, l;
        split3(a[j], h, m, l);
        h4[j] = h; m4[j] = m; l4[j] = l;
      }
      reinterpret_cast<s16x4*>(hs)[i] = h4;
      reinterpret_cast<s16x4*>(ms)[i] = m4;
      reinterpret_cast<s16x4*>(ls)[i] = l4;
    }
  } else if (b < 5120) {
    const int b2 = b - 4096;
    const int k0 = (b2 & 63) * 64;
    const int head = b2 >> 6;
    {
      int r = t >> 2, c = (t & 3) * 16;
      const f32x4* src = reinterpret_cast<const f32x4*>(&V[(size_t)(k0 + r) * DMODEL + head * HDIM + c]);
      #pragma unroll
      for (int j = 0; j < 4; ++j)
        *reinterpret_cast<f32x4*>(&T[r][c + 4 * j]) = src[j];
    }
    __syncthreads();
    {
      int d = t >> 2, kc = (t & 3) * 16;
      s16x8 h8[2], m8[2], l8[2];
      #pragma unroll
      for (int j = 0; j < 16; ++j) {
        float v = T[kc + j][d];
        short h, m, l;
        split3(v, h, m, l);
        h8[j >> 3][j & 7] = h; m8[j >> 3][j & 7] = m; l8[j >> 3][j & 7] = l;
      }
      size_t base = (size_t)(head * HDIM + d) * L_SEQ + k0 + kc;
      *reinterpret_cast<s16x8*>(&Vth[base]) = h8[0];
      *reinterpret_cast<s16x8*>(&Vth[base + 8]) = h8[1];
      *reinterpret_cast<s16x8*>(&Vtm[base]) = m8[0];
      *reinterpret_cast<s16x8*>(&Vtm[base + 8]) = m8[1];
      *reinterpret_cast<s16x8*>(&Vtl[base]) = l8[0];
      *reinterpret_cast<s16x8*>(&Vtl[base + 8]) = l8[1];
    }
  } else {
    const int idx = b - 5120;         // 0..16383
    const int z = idx >> 10;          // 0..15
    const int f = idx & 1023;
    const float* src;
    short* dst;
    int R, C, r0, c0, e;
    if (z < 8) { e = z; R = DMODEL; C = NHID; src = W1; dst = W1t; r0 = (f >> 6) * 64; c0 = (f & 63) * 64; }
    else { e = z - 8; R = NHID; C = DMODEL; src = W2; dst = W2t; r0 = (f >> 4) * 64; c0 = (f & 15) * 64; }
    const size_t sbase = (size_t)e * R * C;
    {
      int rr = t >> 2, cc = (t & 3) * 16;
      #pragma unroll
      for (int j = 0; j < 4; ++j)
        *reinterpret_cast<f32x4*>(&T[rr][cc + 4 * j]) =
            *reinterpret_cast<const f32x4*>(&src[sbase + (size_t)(r0 + rr) * C + c0 + cc + 4 * j]);
    }
    __syncthreads();
    {
      int c = t >> 2, r = (t & 3) * 16;
      s16x8 v0, v1;
      #pragma unroll
      for (int j = 0; j < 8; ++j) { v0[j] = f2bf(T[r + j][c]); v1[j] = f2bf(T[r + 8 + j][c]); }
      size_t dbase = ((size_t)e * C + c0 + c) * R + r0 + r;
      *reinterpret_cast<s16x8*>(&dst[dbase]) = v0;
      *reinterpret_cast<s16x8*>(&dst[dbase + 8]) = v1;
    }
  }
}

// ---------- attention: 32x32x16 MFMA flash, fixed-max softmax, P in registers ----------
__global__ __launch_bounds__(256, 2) void attn_mfma(
    const short* __restrict__ Qh, const short* __restrict__ Qm, const short* __restrict__ Ql,
    const short* __restrict__ Kh, const short* __restrict__ Km, const short* __restrict__ Kl,
    const short* __restrict__ Vth, const short* __restrict__ Vtm, const short* __restrict__ Vtl,
    float* __restrict__ X, short* __restrict__ Xb) {
  __shared__ short Ks[3][64][70];
  __shared__ short Vs[3][64][70];   // transposed: [d][k]
  const int lin = blockIdx.x;                    // 512 blocks
  const int swz = (lin & 7) * 64 + (lin >> 3);   // XCD swizzle (bijective: 512=8*64)
  const int head = swz >> 5;
  const int q0 = (swz & 31) << 7;                // 128-q tile
  const int t = threadIdx.x;
  const int l = t & 63;
  const int wq = t >> 6;
  const int lc = l & 31;
  const int hh = l >> 5;

  const short* Qp[3] = {Qh, Qm, Ql};
  const short* Kp[3] = {Kh, Km, Kl};
  const short* Vp[3] = {Vth, Vtm, Vtl};

  s16x8 qf[3][4];
  {
    size_t qrow = (size_t)(q0 + wq * 32 + lc) * DMODEL + head * HDIM;
    #pragma unroll
    for (int s = 0; s < 3; ++s)
      #pragma unroll
      for (int ds_ = 0; ds_ < 4; ++ds_)
        qf[s][ds_] = *reinterpret_cast<const s16x8*>(&Qp[s][qrow + ds_ * 16 + hh * 8]);
  }

  s16x8 sK[3][2], sV[3][2];
  const int c0 = t * 2;
  const int row0 = c0 >> 3, ch0 = (c0 & 7) * 8;
  const int row1 = (c0 + 1) >> 3, ch1 = ((c0 + 1) & 7) * 8;

  #define LOAD_TILE(k0v)                                                                  \
    _Pragma("unroll")                                                                     \
    for (int s = 0; s < 3; ++s) {                                                         \
      sK[s][0] = *reinterpret_cast<const s16x8*>(&Kp[s][(size_t)((k0v) + row0) * DMODEL + head * HDIM + ch0]); \
      sK[s][1] = *reinterpret_cast<const s16x8*>(&Kp[s][(size_t)((k0v) + row1) * DMODEL + head * HDIM + ch1]); \
      sV[s][0] = *reinterpret_cast<const s16x8*>(&Vp[s][(size_t)(head * HDIM + row0) * L_SEQ + (k0v) + ch0]);  \
      sV[s][1] = *reinterpret_cast<const s16x8*>(&Vp[s][(size_t)(head * HDIM + row1) * L_SEQ + (k0v) + ch1]);  \
    }

  f32x16 acc0 = (f32x16)0.f, acc1 = (f32x16)0.f;
  float l_loc = 0.f;
  const float LOG2E = 1.4426950408889634f;
  const float MBIAS = 46.166241f;

  LOAD_TILE(0);

  for (int kt64 = 0; kt64 < 64; ++kt64) {
    __syncthreads();
    #pragma unroll
    for (int s = 0; s < 3; ++s) {
      *reinterpret_cast<s16x8*>(&Ks[s][row0][ch0]) = sK[s][0];
      *reinterpret_cast<s16x8*>(&Ks[s][row1][ch1]) = sK[s][1];
      *reinterpret_cast<s16x8*>(&Vs[s][row0][ch0]) = sV[s][0];
      *reinterpret_cast<s16x8*>(&Vs[s][row1][ch1]) = sV[s][1];
    }
    __syncthreads();
    if (kt64 < 63) { LOAD_TILE((kt64 + 1) * 64); }

    #pragma unroll
    for (int khalf = 0; khalf < 2; ++khalf) {
      f32x16 st = (f32x16)0.f;
      #pragma unroll
      for (int ds_ = 0; ds_ < 4; ++ds_) {
        s16x8 ah = *reinterpret_cast<const s16x8*>(&Ks[0][khalf * 32 + lc][ds_ * 16 + hh * 8]);
        s16x8 am = *reinterpret_cast<const s16x8*>(&Ks[1][khalf * 32 + lc][ds_ * 16 + hh * 8]);
        s16x8 al = *reinterpret_cast<const s16x8*>(&Ks[2][khalf * 32 + lc][ds_ * 16 + hh * 8]);
        st = __builtin_amdgcn_mfma_f32_32x32x16_bf16(am, qf[1][ds_], st, 0, 0, 0);
        st = __builtin_amdgcn_mfma_f32_32x32x16_bf16(al, qf[0][ds_], st, 0, 0, 0);
        st = __builtin_amdgcn_mfma_f32_32x32x16_bf16(ah, qf[2][ds_], st, 0, 0, 0);
        st = __builtin_amdgcn_mfma_f32_32x32x16_bf16(am, qf[0][ds_], st, 0, 0, 0);
        st = __builtin_amdgcn_mfma_f32_32x32x16_bf16(ah, qf[1][ds_], st, 0, 0, 0);
        st = __builtin_amdgcn_mfma_f32_32x32x16_bf16(ah, qf[0][ds_], st, 0, 0, 0);
      }

      unsigned Eh[4][2], Em[4][2], El[4][2];
      float ps = 0.f;
      #pragma unroll
      for (int q = 0; q < 4; ++q) {
        #pragma unroll
        for (int p = 0; p < 2; ++p) {
          float a = exp2f(fmaf(st[4 * q + 2 * p],     LOG2E, -MBIAS));
          float b = exp2f(fmaf(st[4 * q + 2 * p + 1], LOG2E, -MBIAS));
          ps += a + b;
          unsigned ua = __float_as_uint(a), ub = __float_as_uint(b);
          unsigned ha = ua & 0xffff0000u, hb = ub & 0xffff0000u;
          Eh[q][p] = (ha >> 16) | hb;
          float ra = a - __uint_as_float(ha), rb = b - __uint_as_float(hb);
          unsigned ma = __float_as_uint(ra) & 0xffff0000u, mb = __float_as_uint(rb) & 0xffff0000u;
          Em[q][p] = (ma >> 16) | mb;
          float la = ra - __uint_as_float(ma), lb = rb - __uint_as_float(mb);
          El[q][p] = ((__float_as_uint(la) & 0xffff0000u) >> 16) | (__float_as_uint(lb) & 0xffff0000u);
        }
      }
      l_loc += ps;

      #define EXCH(E, Fout) do { u32x4 f_;                                        \
        _Pragma("unroll") for (int p_ = 0; p_ < 2; ++p_) {                        \
          unsigned sel_ = hh ? E[2 * ks][p_] : E[2 * ks + 1][p_];                 \
          unsigned rc_ = (unsigned)__shfl_xor((int)sel_, 32);                     \
          f_[p_] = hh ? rc_ : E[2 * ks][p_];                                      \
          f_[2 + p_] = hh ? E[2 * ks + 1][p_] : rc_;                              \
        }                                                                         \
        Fout = *reinterpret_cast<s16x8*>(&f_); } while (0)

      #pragma unroll
      for (int ks = 0; ks < 2; ++ks) {
        s16x8 Fh, Fm, Fl;
        EXCH(Eh, Fh);
        EXCH(Em, Fm);
        EXCH(El, Fl);
        const int kcol = khalf * 32 + ks * 16 + hh * 8;
        {
          s16x8 vh = *reinterpret_cast<const s16x8*>(&Vs[0][lc][kcol]);
          s16x8 vm = *reinterpret_cast<const s16x8*>(&Vs[1][lc][kcol]);
          s16x8 vl = *reinterpret_cast<const s16x8*>(&Vs[2][lc][kcol]);
          acc0 = __builtin_amdgcn_mfma_f32_32x32x16_bf16(Fm, vm, acc0, 0, 0, 0);
          acc0 = __builtin_amdgcn_mfma_f32_32x32x16_bf16(Fl, vh, acc0, 0, 0, 0);
          acc0 = __builtin_amdgcn_mfma_f32_32x32x16_bf16(Fh, vl, acc0, 0, 0, 0);
          acc0 = __builtin_amdgcn_mfma_f32_32x32x16_bf16(Fm, vh, acc0, 0, 0, 0);
          acc0 = __builtin_amdgcn_mfma_f32_32x32x16_bf16(Fh, vm, acc0, 0, 0, 0);
          acc0 = __builtin_amdgcn_mfma_f32_32x32x16_bf16(Fh, vh, acc0, 0, 0, 0);
        }
        {
          s16x8 vh = *reinterpret_cast<const s16x8*>(&Vs[0][32 + lc][kcol]);
          s16x8 vm = *reinterpret_cast<const s16x8*>(&Vs[1][32 + lc][kcol]);
          s16x8 vl = *reinterpret_cast<const s16x8*>(&Vs[2][32 + lc][kcol]);
          acc1 = __builtin_amdgcn_mfma_f32_32x32x16_bf16(Fm, vm, acc1, 0, 0, 0);
          acc1 = __builtin_amdgcn_mfma_f32_32x32x16_bf16(Fl, vh, acc1, 0, 0, 0);
          acc1 = __builtin_amdgcn_mfma_f32_32x32x16_bf16(Fh, vl, acc1, 0, 0, 0);
          acc1 = __builtin_amdgcn_mfma_f32_32x32x16_bf16(Fm, vh, acc1, 0, 0, 0);
          acc1 = __builtin_amdgcn_mfma_f32_32x32x16_bf16(Fh, vm, acc1, 0, 0, 0);
          acc1 = __builtin_amdgcn_mfma_f32_32x32x16_bf16(Fh, vh, acc1, 0, 0, 0);
        }
      }
      #undef EXCH
    }
  }

  float l_tot = l_loc + __shfl_xor(l_loc, 32);
  float inv = 1.f / l_tot;
  #pragma unroll
  for (int r = 0; r < 16; ++r) {
    int qrow_ = (r & 3) + 8 * (r >> 2) + 4 * hh;
    float invr = __int_as_float(__builtin_amdgcn_ds_bpermute(qrow_ << 2, __float_as_int(inv)));
    size_t base = (size_t)(q0 + wq * 32 + qrow_) * DMODEL + head * HDIM + lc;
    float o0 = acc0[r] * invr, o1 = acc1[r] * invr;
    X[base] = o0;
    X[base + 32] = o1;
    Xb[base] = f2bf(o0);
    Xb[base + 32] = f2bf(o1);
  }
}

// ---------------- gating: one wave per token, f64 accumulation ----------------
__global__ __launch_bounds__(256) void gate_kernel(const float* __restrict__ X,
                                                   const float* __restrict__ GW,
                                                   int* __restrict__ tokE,
                                                   float* __restrict__ tokW,
                                                   int* __restrict__ meta) {
  const int gid = blockIdx.x * 256 + threadIdx.x;
  const int n = gid >> 6;
  const int lane = threadIdx.x & 63;
  double lacc[8];
  #pragma unroll
  for (int e = 0; e < 8; ++e) lacc[e] = 0.0;
  #pragma unroll
  for (int ch = 0; ch < 4; ++ch) {
    int d0 = ch * 256 + lane * 4;
    f32x4 xv = *reinterpret_cast<const f32x4*>(&X[(size_t)n * DMODEL + d0]);
    #pragma unroll
    for (int j = 0; j < 4; ++j) {
      const f32x4* g = reinterpret_cast<const f32x4*>(&GW[(size_t)(d0 + j) * 8]);
      f32x4 g0 = g[0], g1 = g[1];
      double xd = (double)xv[j];
      lacc[0] += xd * (double)g0[0]; lacc[1] += xd * (double)g0[1];
      lacc[2] += xd * (double)g0[2]; lacc[3] += xd * (double)g0[3];
      lacc[4] += xd * (double)g1[0]; lacc[5] += xd * (double)g1[1];
      lacc[6] += xd * (double)g1[2]; lacc[7] += xd * (double)g1[3];
    }
  }
  #pragma unroll
  for (int e = 0; e < 8; ++e) {
    double v = lacc[e];
    #pragma unroll
    for (int off = 32; off > 0; off >>= 1) v += __shfl_down(v, off);
    lacc[e] = v;
  }
  if (lane == 0) {
    float lg[8];
    #pragma unroll
    for (int e = 0; e < 8; ++e) lg[e] = (float)lacc[e];
    int i0 = 0;
    for (int e = 1; e < 8; ++e) if (lg[e] > lg[i0]) i0 = e;
    int i1 = -1;
    for (int e = 0; e < 8; ++e) {
      if (e == i0) continue;
      if (i1 < 0 || lg[e] > lg[i1]) i1 = e;
    }
    float eb = expf(lg[i1] - lg[i0]);
    float wa = 1.f / (1.f + eb);
    float wb = eb * wa;
    tokE[2 * n] = i0; tokE[2 * n + 1] = i1;
    tokW[2 * n] = wa; tokW[2 * n + 1] = wb;
    atomicAdd(&meta[i0], 1);
    atomicAdd(&meta[i1], 1);
  }
}

// ---------- fused scan (thread 0) + assign (all 256 threads), single block ----------
// meta: [0..7]=cnt, [8..15]=base, [16..23]=cursor. map: 80x{e,m0} 128-row tiles.
__global__ __launch_bounds__(256) void scanassign_kernel(const int* __restrict__ tokE,
                                                         const float* __restrict__ tokW,
                                                         int* __restrict__ meta,
                                                         int* __restrict__ map,
                                                         int* __restrict__ list,
                                                         float* __restrict__ wl) {
  if (threadIdx.x == 0) {
    int s = 0, c = 0;
    for (int e = 0; e < 8; ++e) {
      meta[8 + e] = s; meta[16 + e] = s;
      int cnt = meta[e];
      for (int m0 = 0; m0 < cnt; m0 += 128) { map[2 * c] = e; map[2 * c + 1] = m0; ++c; }
      s += cnt;
    }
    for (; c < 80; ++c) map[2 * c] = -1;
  }
  __syncthreads();
  for (int n = threadIdx.x; n < L_SEQ; n += 256) {
    #pragma unroll
    for (int k2 = 0; k2 < 2; ++k2) {
      int e = tokE[2 * n + k2];
      int slot = atomicAdd(&meta[16 + e], 1);
      list[slot] = n;
      wl[slot] = tokW[2 * n + k2];
    }
  }
}

// ============ expert GEMMs (R10/R12 internals) + XCD m-panel grouping ============
// flat dispatch id -> xcd = flat&7; each XCD owns 10 consecutive map entries (m-tiles,
// expert-sorted) x all n-tiles -> A- and B-panels stay in that XCD's L2.
__global__ __launch_bounds__(256) void gemm1p_kernel(const short* __restrict__ Xb,
                                                     const short* __restrict__ W1t,
                                                     const float* __restrict__ B1,
                                                     const int* __restrict__ meta,
                                                     const int* __restrict__ list,
                                                     const int* __restrict__ map,
                                                     short* __restrict__ Hb) {
  const int flat = blockIdx.x + gridDim.x * blockIdx.y;  // 0..2559
  const int xcd = flat & 7;
  const int idx = flat >> 3;                              // 0..319
  const int mIdx = xcd * 10 + (idx >> 5);                 // 0..79
  const int e = map[2 * mIdx];
  if (e < 0) return;
  const int m0 = map[2 * mIdx + 1];
  const int n0 = (idx & 31) << 7;
  const int cntE = meta[e];
  const int baseE = meta[8 + e];

  __shared__ short As[3][128 * 32];
  __shared__ short Bs[3][128 * 32];

  const int t = threadIdx.x;
  const int l = t & 63;
  const int w = t >> 6;
  const int wm = w >> 1, wn = w & 1;
  const int ln = l & 15, kg = l >> 4;

  size_t asrc[2], bsrc[2];
  #pragma unroll
  for (int c = 0; c < 2; ++c) {
    int idx2 = c * 256 + t;
    int row = idx2 >> 2;
    int sch = (idx2 & 3) ^ ((row >> 2) & 3);
    int idxm = m0 + row; if (idxm > cntE - 1) idxm = cntE - 1;
    int grow = list[baseE + idxm];
    asrc[c] = ((size_t)grow * DMODEL + sch * 8) * 2;
    bsrc[c] = (((size_t)e * NHID + n0 + row) * DMODEL + sch * 8) * 2;
  }

  f32x4 acc[4][4];
  #pragma unroll
  for (int mi = 0; mi < 4; ++mi)
    #pragma unroll
    for (int ni = 0; ni < 4; ++ni) acc[mi][ni] = (f32x4)0.f;

  #define STG1(h_, bf_) do { size_t ko_ = (size_t)(h_) * 64;                        \
    _Pragma("unroll")                                                               \
    for (int c_ = 0; c_ < 2; ++c_) {                                                \
      gload16((const char*)Xb + asrc[c_] + ko_, (char*)As + (bf_) * 8192 + c_ * 4096 + t * 16);  \
      gload16((const char*)W1t + bsrc[c_] + ko_, (char*)Bs + (bf_) * 8192 + c_ * 4096 + t * 16); \
    } } while (0)

  const int H = DMODEL / 32;   // 32
  STG1(0, 0); STG1(1, 1);
  for (int h = 0; h < H; ++h) {
    if (h < H - 1) asm volatile("s_waitcnt vmcnt(4)\ns_barrier" ::: "memory");
    else           asm volatile("s_waitcnt vmcnt(0)\ns_barrier" ::: "memory");
    if (h + 2 < H) STG1(h + 2, (h + 2) % 3);
    const char* ab = (const char*)As + (h % 3) * 8192;
    const char* bb = (const char*)Bs + (h % 3) * 8192;
    s16x8 af[4];
    #pragma unroll
    for (int mi = 0; mi < 4; ++mi) {
      int row = wm * 64 + mi * 16 + ln;
      int cc = kg ^ ((row >> 2) & 3);
      af[mi] = *reinterpret_cast<const s16x8*>(ab + row * 64 + cc * 16);
    }
    #pragma unroll
    for (int ni = 0; ni < 4; ++ni) {
      int col = wn * 64 + ni * 16 + ln;
      int cc = kg ^ ((col >> 2) & 3);
      s16x8 bfr = *reinterpret_cast<const s16x8*>(bb + col * 64 + cc * 16);
      #pragma unroll
      for (int mi = 0; mi < 4; ++mi)
        acc[mi][ni] = __builtin_amdgcn_mfma_f32_16x16x32_bf16(af[mi], bfr, acc[mi][ni], 0, 0, 0);
    }
  }

  #pragma unroll
  for (int mi = 0; mi < 4; ++mi) {
    #pragma unroll
    for (int r = 0; r < 4; ++r) {
      int rl = wm * 64 + mi * 16 + kg * 4 + r;
      if (m0 + rl >= cntE) continue;
      size_t hrow = (size_t)(baseE + m0 + rl) * NHID;
      #pragma unroll
      for (int ni = 0; ni < 4; ++ni) {
        int col = n0 + wn * 64 + ni * 16 + ln;
        float z = acc[mi][ni][r] + B1[e * NHID + col];
        float g = 0.5f * z * (1.f + erff(z * 0.70710678118f));
        Hb[hrow + col] = f2bf(g);
      }
    }
  }
}

__global__ __launch_bounds__(256) void gemm2p_kernel(const short* __restrict__ Hb,
                                                     const short* __restrict__ W2t,
                                                     const float* __restrict__ B2,
                                                     const int* __restrict__ meta,
                                                     const int* __restrict__ list,
                                                     const float* __restrict__ wl,
                                                     const int* __restrict__ map,
                                                     float* __restrict__ out) {
  const int flat = blockIdx.x + gridDim.x * blockIdx.y;  // 0..639
  const int xcd = flat & 7;
  const int idx = flat >> 3;                              // 0..79
  const int mIdx = xcd * 10 + (idx >> 3);                 // 0..79
  const int e = map[2 * mIdx];
  if (e < 0) return;
  const int m0 = map[2 * mIdx + 1];
  const int n0 = (idx & 7) << 7;
  const int cntE = meta[e];
  const int baseE = meta[8 + e];

  __shared__ short As[3][128 * 32];
  __shared__ short Bs[3][128 * 32];

  const int t = threadIdx.x;
  const int l = t & 63;
  const int w = t >> 6;
  const int wm = w >> 1, wn = w & 1;
  const int ln = l & 15, kg = l >> 4;

  size_t asrc[2], bsrc[2];
  #pragma unroll
  for (int c = 0; c < 2; ++c) {
    int idx2 = c * 256 + t;
    int row = idx2 >> 2;
    int sch = (idx2 & 3) ^ ((row >> 2) & 3);
    int idxm = m0 + row; if (idxm > cntE - 1) idxm = cntE - 1;
    asrc[c] = (((size_t)(baseE + idxm)) * NHID + sch * 8) * 2;
    bsrc[c] = (((size_t)e * DMODEL + n0 + row) * NHID + sch * 8) * 2;
  }

  f32x4 acc[4][4];
  #pragma unroll
  for (int mi = 0; mi < 4; ++mi)
    #pragma unroll
    for (int ni = 0; ni < 4; ++ni) acc[mi][ni] = (f32x4)0.f;

  #define STG2(h_, bf_) do { size_t ko_ = (size_t)(h_) * 64;                        \
    _Pragma("unroll")                                                               \
    for (int c_ = 0; c_ < 2; ++c_) {                                                \
      gload16((const char*)Hb + asrc[c_] + ko_, (char*)As + (bf_) * 8192 + c_ * 4096 + t * 16);  \
      gload16((const char*)W2t + bsrc[c_] + ko_, (char*)Bs + (bf_) * 8192 + c_ * 4096 + t * 16); \
    } } while (0)

  const int H = NHID / 32;   // 128
  STG2(0, 0); STG2(1, 1);
  for (int h = 0; h < H; ++h) {
    if (h < H - 1) asm volatile("s_waitcnt vmcnt(4)\ns_barrier" ::: "memory");
    else           asm volatile("s_waitcnt vmcnt(0)\ns_barrier" ::: "memory");
    if (h + 2 < H) STG2(h + 2, (h + 2) % 3);
    const char* ab = (const char*)As + (h % 3) * 8192;
    const char* bb = (const char*)Bs + (h % 3) * 8192;
    s16x8 af[4];
    #pragma unroll
    for (int mi = 0; mi < 4; ++mi) {
      int row = wm * 64 + mi * 16 + ln;
      int cc = kg ^ ((row >> 2) & 3);
      af[mi] = *reinterpret_cast<const s16x8*>(ab + row * 64 + cc * 16);
    }
    #pragma unroll
    for (int ni = 0; ni < 4; ++ni) {
      int col = wn * 64 + ni * 16 + ln;
      int cc = kg ^ ((col >> 2) & 3);
      s16x8 bfr = *reinterpret_cast<const s16x8*>(bb + col * 64 + cc * 16);
      #pragma unroll
      for (int mi = 0; mi < 4; ++mi)
        acc[mi][ni] = __builtin_amdgcn_mfma_f32_16x16x32_bf16(af[mi], bfr, acc[mi][ni], 0, 0, 0);
    }
  }

  #pragma unroll
  for (int mi = 0; mi < 4; ++mi) {
    #pragma unroll
    for (int r = 0; r < 4; ++r) {
      int rl = wm * 64 + mi * 16 + kg * 4 + r;
      if (m0 + rl >= cntE) continue;
      int slot = baseE + m0 + rl;
      int token = list[slot];
      float wgt = wl[slot];
      #pragma unroll
      for (int ni = 0; ni < 4; ++ni) {
        int col = n0 + wn * 64 + ni * 16 + ln;
        float z = acc[mi][ni][r] + B2[e * DMODEL + col];
        atomicAdd(&out[(size_t)token * DMODEL + col], wgt * z);
      }
    }
  }
}

extern "C" void kernel_launch(void* const* d_in, const int* in_sizes, int n_in,
                              void* d_out, int out_size, void* d_ws, size_t ws_size,
                              hipStream_t stream) {
  const float* Q  = (const float*)d_in[0];
  const float* K  = (const float*)d_in[1];
  const float* V  = (const float*)d_in[2];
  const float* GW = (const float*)d_in[3];
  const float* W1 = (const float*)d_in[4];
  const float* B1 = (const float*)d_in[5];
  const float* W2 = (const float*)d_in[6];
  const float* B2 = (const float*)d_in[7];
  float* out = (float*)d_out;

  const size_t SPLIT = (size_t)L_SEQ * DMODEL;
  const size_t WT_BYTES = (size_t)NEXP * NHID * DMODEL * 2;
  const size_t SPLIT_REGION = SPLIT * 2 * 9;
  const size_t SMALL = (size_t)L_SEQ * 2 * 4 * 2 + (size_t)NSLOT * 4 * 2 + 4096;
  const size_t PRIMARY_BYTES = WT_BYTES * 2 + SPLIT_REGION + SPLIT * 4 + SPLIT * 2 + SMALL;
  if (ws_size < PRIMARY_BYTES) return;

  char* ws = (char*)d_ws;

  size_t off = 0;
  short* W1t = (short*)(ws + off); off += WT_BYTES;
  short* W2t = (short*)(ws + off); off += WT_BYTES;
  char*  splits = ws + off;        off += SPLIT_REGION;
  short* Qh = (short*)(splits);
  short* Qm = Qh + SPLIT;  short* Ql = Qm + SPLIT;
  short* Kh = Ql + SPLIT;  short* Km = Kh + SPLIT;  short* Kl = Km + SPLIT;
  short* Vth = Kl + SPLIT; short* Vtm = Vth + SPLIT; short* Vtl = Vtm + SPLIT;
  short* Hb = (short*)splits;                       // aliases splits AFTER attn
  float* Xf = (float*)(ws + off);  off += SPLIT * 4;
  short* Xb = (short*)(ws + off);  off += SPLIT * 2; // dedicated (live during attn)
  int*   tokE = (int*)(ws + off);  off += (size_t)L_SEQ * 2 * 4;
  float* tokW = (float*)(ws + off); off += (size_t)L_SEQ * 2 * 4;
  int*   list = (int*)(ws + off);  off += (size_t)NSLOT * 4;
  float* wl = (float*)(ws + off);  off += (size_t)NSLOT * 4;
  int*   meta = (int*)(ws + off);  off += 256;
  int*   map = (int*)(ws + off);   off += 80 * 2 * 4;

  hipMemsetAsync(out, 0, (size_t)out_size * sizeof(float), stream);
  hipMemsetAsync(meta, 0, 256, stream);

  prep_kernel<<<dim3(21504), 256, 0, stream>>>(Q, K, V, W1, W2,
                                               Qh, Qm, Ql, Kh, Km, Kl, Vth, Vtm, Vtl,
                                               W1t, W2t);
  attn_mfma<<<dim3(512), 256, 0, stream>>>(Qh, Qm, Ql, Kh, Km, Kl, Vth, Vtm, Vtl, Xf, Xb);
  gate_kernel<<<dim3(1024), 256, 0, stream>>>(Xf, GW, tokE, tokW, meta);
  scanassign_kernel<<<dim3(1), 256, 0, stream>>>(tokE, tokW, meta, map, list, wl);
  gemm1p_kernel<<<dim3(80, 32), 256, 0, stream>>>(Xb, W1t, B1, meta, list, map, Hb);
  gemm2p_kernel<<<dim3(80, 8), 256, 0, stream>>>(Hb, W2t, B2, meta, list, wl, map, out);
}

// Round 14
// 993.238 us; speedup vs baseline: 1.0002x; 1.0002x over previous
//
#include <hip/hip_runtime.h>
#include <hip/hip_bf16.h>
#include <math.h>

#define L_SEQ 4096
#define DMODEL 1024
#define NHEAD 16
#define HDIM 64
#define NEXP 8
#define NHID 4096
#define NSLOT (L_SEQ * 2)

typedef __attribute__((ext_vector_type(4))) float f32x4;
typedef __attribute__((ext_vector_type(16))) float f32x16;
typedef __attribute__((ext_vector_type(8))) short s16x8;
typedef __attribute__((ext_vector_type(4))) short s16x4;
typedef __attribute__((ext_vector_type(4))) unsigned u32x4;

__device__ __forceinline__ short f2bf(float f) {
  __hip_bfloat16 h = __float2bfloat16(f);
  return *reinterpret_cast<short*>(&h);
}
__device__ __forceinline__ float bf2f(short s) {
  __hip_bfloat16 h;
  *reinterpret_cast<short*>(&h) = s;
  return __bfloat162float(h);
}
__device__ __forceinline__ void split3(float a, short& h, short& m, short& l) {
  h = f2bf(a);
  float r = a - bf2f(h);
  m = f2bf(r);
  float r2 = r - bf2f(m);
  l = f2bf(r2);
}
__device__ __forceinline__ void gload16(const void* g, void* l) {
  __builtin_amdgcn_global_load_lds(
      (const __attribute__((address_space(1))) void*)g,
      (__attribute__((address_space(3))) void*)l, 16, 0, 0);
}

// ---------- fused pre-pass ----------
// blocks 0..2047: split Q | 2048..4095: split K | 4096..5119: V transpose-split
// blocks 5120..21503: weight transpose (idx>>10 = z role: z<8 -> W1, else W2)
__global__ __launch_bounds__(256) void prep_kernel(
    const float* __restrict__ Q, const float* __restrict__ K, const float* __restrict__ V,
    const float* __restrict__ W1, const float* __restrict__ W2,
    short* __restrict__ Qh, short* __restrict__ Qm, short* __restrict__ Ql,
    short* __restrict__ Kh, short* __restrict__ Km, short* __restrict__ Kl,
    short* __restrict__ Vth, short* __restrict__ Vtm, short* __restrict__ Vtl,
    short* __restrict__ W1t, short* __restrict__ W2t) {
  __shared__ float T[64][65];
  const int b = blockIdx.x;
  const int t = threadIdx.x;
  if (b < 4096) {
    const bool isQ = (b < 2048);
    const float* src = isQ ? Q : K;
    short* hs = isQ ? Qh : Kh;
    short* ms = isQ ? Qm : Km;
    short* ls = isQ ? Ql : Kl;
    const float scale = isQ ? 0.125f : 1.0f;
    const int nquad = (int)((size_t)L_SEQ * DMODEL / 4);
    int i = (b & 2047) * 256 + t;
    for (; i < nquad; i += 2048 * 256) {
      f32x4 a = reinterpret_cast<const f32x4*>(src)[i];
      a *= scale;
      s16x4 h4, m4, l4;
      #pragma unroll
      for (int j = 0; j < 4; ++j) {
        short h, m, l;
        split3(a[j], h, m, l);
        h4[j] = h; m4[j] = m; l4[j] = l;
      }
      reinterpret_cast<s16x4*>(hs)[i] = h4;
      reinterpret_cast<s16x4*>(ms)[i] = m4;
      reinterpret_cast<s16x4*>(ls)[i] = l4;
    }
  } else if (b < 5120) {
    const int b2 = b - 4096;
    const int k0 = (b2 & 63) * 64;
    const int head = b2 >> 6;
    {
      int r = t >> 2, c = (t & 3) * 16;
      const f32x4* src = reinterpret_cast<const f32x4*>(&V[(size_t)(k0 + r) * DMODEL + head * HDIM + c]);
      #pragma unroll
      for (int j = 0; j < 4; ++j)
        *reinterpret_cast<f32x4*>(&T[r][c + 4 * j]) = src[j];
    }
    __syncthreads();
    {
      int d = t >> 2, kc = (t & 3) * 16;
      s16x8 h8[2], m8[2], l8[2];
      #pragma unroll
      for (int j = 0; j < 16; ++j) {
        float v = T[kc + j][d];
        short h, m, l;
        split3(v, h, m, l);
        h8[j >> 3][j & 7] = h; m8[j >> 3][j & 7] = m; l8[j >> 3][j & 7] = l;
      }
      size_t base = (size_t)(head * HDIM + d) * L_SEQ + k0 + kc;
      *reinterpret_cast<s16x8*>(&Vth[base]) = h8[0];
      *reinterpret_cast<s16x8*>(&Vth[base + 8]) = h8[1];
      *reinterpret_cast<s16x8*>(&Vtm[base]) = m8[0];
      *reinterpret_cast<s16x8*>(&Vtm[base + 8]) = m8[1];
      *reinterpret_cast<s16x8*>(&Vtl[base]) = l8[0];
      *reinterpret_cast<s16x8*>(&Vtl[base + 8]) = l8[1];
    }
  } else {
    const int idx = b - 5120;         // 0..16383
    const int z = idx >> 10;          // 0..15
    const int f = idx & 1023;
    const float* src;
    short* dst;
    int R, C, r0, c0, e;
    if (z < 8) { e = z; R = DMODEL; C = NHID; src = W1; dst = W1t; r0 = (f >> 6) * 64; c0 = (f & 63) * 64; }
    else { e = z - 8; R = NHID; C = DMODEL; src = W2; dst = W2t; r0 = (f >> 4) * 64; c0 = (f & 15) * 64; }
    const size_t sbase = (size_t)e * R * C;
    {
      int rr = t >> 2, cc = (t & 3) * 16;
      #pragma unroll
      for (int j = 0; j < 4; ++j)
        *reinterpret_cast<f32x4*>(&T[rr][cc + 4 * j]) =
            *reinterpret_cast<const f32x4*>(&src[sbase + (size_t)(r0 + rr) * C + c0 + cc + 4 * j]);
    }
    __syncthreads();
    {
      int c = t >> 2, r = (t & 3) * 16;
      s16x8 v0, v1;
      #pragma unroll
      for (int j = 0; j < 8; ++j) { v0[j] = f2bf(T[r + j][c]); v1[j] = f2bf(T[r + 8 + j][c]); }
      size_t dbase = ((size_t)e * C + c0 + c) * R + r0 + r;
      *reinterpret_cast<s16x8*>(&dst[dbase]) = v0;
      *reinterpret_cast<s16x8*>(&dst[dbase + 8]) = v1;
    }
  }
}

// ---------- attention: 32x32x16 MFMA flash, fixed-max softmax, P in registers ----------
__global__ __launch_bounds__(256, 2) void attn_mfma(
    const short* __restrict__ Qh, const short* __restrict__ Qm, const short* __restrict__ Ql,
    const short* __restrict__ Kh, const short* __restrict__ Km, const short* __restrict__ Kl,
    const short* __restrict__ Vth, const short* __restrict__ Vtm, const short* __restrict__ Vtl,
    float* __restrict__ X, short* __restrict__ Xb) {
  __shared__ short Ks[3][64][70];
  __shared__ short Vs[3][64][70];   // transposed: [d][k]
  const int lin = blockIdx.x;                    // 512 blocks
  const int swz = (lin & 7) * 64 + (lin >> 3);   // XCD swizzle (bijective: 512=8*64)
  const int head = swz >> 5;
  const int q0 = (swz & 31) << 7;                // 128-q tile
  const int t = threadIdx.x;
  const int l = t & 63;
  const int wq = t >> 6;
  const int lc = l & 31;
  const int hh = l >> 5;

  const short* Qp[3] = {Qh, Qm, Ql};
  const short* Kp[3] = {Kh, Km, Kl};
  const short* Vp[3] = {Vth, Vtm, Vtl};

  s16x8 qf[3][4];
  {
    size_t qrow = (size_t)(q0 + wq * 32 + lc) * DMODEL + head * HDIM;
    #pragma unroll
    for (int s = 0; s < 3; ++s)
      #pragma unroll
      for (int ds_ = 0; ds_ < 4; ++ds_)
        qf[s][ds_] = *reinterpret_cast<const s16x8*>(&Qp[s][qrow + ds_ * 16 + hh * 8]);
  }

  s16x8 sK[3][2], sV[3][2];
  const int c0 = t * 2;
  const int row0 = c0 >> 3, ch0 = (c0 & 7) * 8;
  const int row1 = (c0 + 1) >> 3, ch1 = ((c0 + 1) & 7) * 8;

  #define LOAD_TILE(k0v)                                                                  \
    _Pragma("unroll")                                                                     \
    for (int s = 0; s < 3; ++s) {                                                         \
      sK[s][0] = *reinterpret_cast<const s16x8*>(&Kp[s][(size_t)((k0v) + row0) * DMODEL + head * HDIM + ch0]); \
      sK[s][1] = *reinterpret_cast<const s16x8*>(&Kp[s][(size_t)((k0v) + row1) * DMODEL + head * HDIM + ch1]); \
      sV[s][0] = *reinterpret_cast<const s16x8*>(&Vp[s][(size_t)(head * HDIM + row0) * L_SEQ + (k0v) + ch0]);  \
      sV[s][1] = *reinterpret_cast<const s16x8*>(&Vp[s][(size_t)(head * HDIM + row1) * L_SEQ + (k0v) + ch1]);  \
    }

  f32x16 acc0 = (f32x16)0.f, acc1 = (f32x16)0.f;
  float l_loc = 0.f;
  const float LOG2E = 1.4426950408889634f;
  const float MBIAS = 46.166241f;

  LOAD_TILE(0);

  for (int kt64 = 0; kt64 < 64; ++kt64) {
    __syncthreads();
    #pragma unroll
    for (int s = 0; s < 3; ++s) {
      *reinterpret_cast<s16x8*>(&Ks[s][row0][ch0]) = sK[s][0];
      *reinterpret_cast<s16x8*>(&Ks[s][row1][ch1]) = sK[s][1];
      *reinterpret_cast<s16x8*>(&Vs[s][row0][ch0]) = sV[s][0];
      *reinterpret_cast<s16x8*>(&Vs[s][row1][ch1]) = sV[s][1];
    }
    __syncthreads();
    if (kt64 < 63) { LOAD_TILE((kt64 + 1) * 64); }

    #pragma unroll
    for (int khalf = 0; khalf < 2; ++khalf) {
      f32x16 st = (f32x16)0.f;
      #pragma unroll
      for (int ds_ = 0; ds_ < 4; ++ds_) {
        s16x8 ah = *reinterpret_cast<const s16x8*>(&Ks[0][khalf * 32 + lc][ds_ * 16 + hh * 8]);
        s16x8 am = *reinterpret_cast<const s16x8*>(&Ks[1][khalf * 32 + lc][ds_ * 16 + hh * 8]);
        s16x8 al = *reinterpret_cast<const s16x8*>(&Ks[2][khalf * 32 + lc][ds_ * 16 + hh * 8]);
        st = __builtin_amdgcn_mfma_f32_32x32x16_bf16(am, qf[1][ds_], st, 0, 0, 0);
        st = __builtin_amdgcn_mfma_f32_32x32x16_bf16(al, qf[0][ds_], st, 0, 0, 0);
        st = __builtin_amdgcn_mfma_f32_32x32x16_bf16(ah, qf[2][ds_], st, 0, 0, 0);
        st = __builtin_amdgcn_mfma_f32_32x32x16_bf16(am, qf[0][ds_], st, 0, 0, 0);
        st = __builtin_amdgcn_mfma_f32_32x32x16_bf16(ah, qf[1][ds_], st, 0, 0, 0);
        st = __builtin_amdgcn_mfma_f32_32x32x16_bf16(ah, qf[0][ds_], st, 0, 0, 0);
      }

      unsigned Eh[4][2], Em[4][2], El[4][2];
      float ps = 0.f;
      #pragma unroll
      for (int q = 0; q < 4; ++q) {
        #pragma unroll
        for (int p = 0; p < 2; ++p) {
          float a = exp2f(fmaf(st[4 * q + 2 * p],     LOG2E, -MBIAS));
          float b = exp2f(fmaf(st[4 * q + 2 * p + 1], LOG2E, -MBIAS));
          ps += a + b;
          unsigned ua = __float_as_uint(a), ub = __float_as_uint(b);
          unsigned ha = ua & 0xffff0000u, hb = ub & 0xffff0000u;
          Eh[q][p] = (ha >> 16) | hb;
          float ra = a - __uint_as_float(ha), rb = b - __uint_as_float(hb);
          unsigned ma = __float_as_uint(ra) & 0xffff0000u, mb = __float_as_uint(rb) & 0xffff0000u;
          Em[q][p] = (ma >> 16) | mb;
          float la = ra - __uint_as_float(ma), lb = rb - __uint_as_float(mb);
          El[q][p] = ((__float_as_uint(la) & 0xffff0000u) >> 16) | (__float_as_uint(lb) & 0xffff0000u);
        }
      }
      l_loc += ps;

      #define EXCH(E, Fout) do { u32x4 f_;                                        \
        _Pragma("unroll") for (int p_ = 0; p_ < 2; ++p_) {                        \
          unsigned sel_ = hh ? E[2 * ks][p_] : E[2 * ks + 1][p_];                 \
          unsigned rc_ = (unsigned)__shfl_xor((int)sel_, 32);                     \
          f_[p_] = hh ? rc_ : E[2 * ks][p_];                                      \
          f_[2 + p_] = hh ? E[2 * ks + 1][p_] : rc_;                              \
        }                                                                         \
        Fout = *reinterpret_cast<s16x8*>(&f_); } while (0)

      #pragma unroll
      for (int ks = 0; ks < 2; ++ks) {
        s16x8 Fh, Fm, Fl;
        EXCH(Eh, Fh);
        EXCH(Em, Fm);
        EXCH(El, Fl);
        const int kcol = khalf * 32 + ks * 16 + hh * 8;
        {
          s16x8 vh = *reinterpret_cast<const s16x8*>(&Vs[0][lc][kcol]);
          s16x8 vm = *reinterpret_cast<const s16x8*>(&Vs[1][lc][kcol]);
          s16x8 vl = *reinterpret_cast<const s16x8*>(&Vs[2][lc][kcol]);
          acc0 = __builtin_amdgcn_mfma_f32_32x32x16_bf16(Fm, vm, acc0, 0, 0, 0);
          acc0 = __builtin_amdgcn_mfma_f32_32x32x16_bf16(Fl, vh, acc0, 0, 0, 0);
          acc0 = __builtin_amdgcn_mfma_f32_32x32x16_bf16(Fh, vl, acc0, 0, 0, 0);
          acc0 = __builtin_amdgcn_mfma_f32_32x32x16_bf16(Fm, vh, acc0, 0, 0, 0);
          acc0 = __builtin_amdgcn_mfma_f32_32x32x16_bf16(Fh, vm, acc0, 0, 0, 0);
          acc0 = __builtin_amdgcn_mfma_f32_32x32x16_bf16(Fh, vh, acc0, 0, 0, 0);
        }
        {
          s16x8 vh = *reinterpret_cast<const s16x8*>(&Vs[0][32 + lc][kcol]);
          s16x8 vm = *reinterpret_cast<const s16x8*>(&Vs[1][32 + lc][kcol]);
          s16x8 vl = *reinterpret_cast<const s16x8*>(&Vs[2][32 + lc][kcol]);
          acc1 = __builtin_amdgcn_mfma_f32_32x32x16_bf16(Fm, vm, acc1, 0, 0, 0);
          acc1 = __builtin_amdgcn_mfma_f32_32x32x16_bf16(Fl, vh, acc1, 0, 0, 0);
          acc1 = __builtin_amdgcn_mfma_f32_32x32x16_bf16(Fh, vl, acc1, 0, 0, 0);
          acc1 = __builtin_amdgcn_mfma_f32_32x32x16_bf16(Fm, vh, acc1, 0, 0, 0);
          acc1 = __builtin_amdgcn_mfma_f32_32x32x16_bf16(Fh, vm, acc1, 0, 0, 0);
          acc1 = __builtin_amdgcn_mfma_f32_32x32x16_bf16(Fh, vh, acc1, 0, 0, 0);
        }
      }
      #undef EXCH
    }
  }

  float l_tot = l_loc + __shfl_xor(l_loc, 32);
  float inv = 1.f / l_tot;
  #pragma unroll
  for (int r = 0; r < 16; ++r) {
    int qrow_ = (r & 3) + 8 * (r >> 2) + 4 * hh;
    float invr = __int_as_float(__builtin_amdgcn_ds_bpermute(qrow_ << 2, __float_as_int(inv)));
    size_t base = (size_t)(q0 + wq * 32 + qrow_) * DMODEL + head * HDIM + lc;
    float o0 = acc0[r] * invr, o1 = acc1[r] * invr;
    X[base] = o0;
    X[base + 32] = o1;
    Xb[base] = f2bf(o0);
    Xb[base + 32] = f2bf(o1);
  }
}

// ---------------- gating: one wave per token, f64 accumulation ----------------
__global__ __launch_bounds__(256) void gate_kernel(const float* __restrict__ X,
                                                   const float* __restrict__ GW,
                                                   int* __restrict__ tokE,
                                                   float* __restrict__ tokW,
                                                   int* __restrict__ meta) {
  const int gid = blockIdx.x * 256 + threadIdx.x;
  const int n = gid >> 6;
  const int lane = threadIdx.x & 63;
  double lacc[8];
  #pragma unroll
  for (int e = 0; e < 8; ++e) lacc[e] = 0.0;
  #pragma unroll
  for (int ch = 0; ch < 4; ++ch) {
    int d0 = ch * 256 + lane * 4;
    f32x4 xv = *reinterpret_cast<const f32x4*>(&X[(size_t)n * DMODEL + d0]);
    #pragma unroll
    for (int j = 0; j < 4; ++j) {
      const f32x4* g = reinterpret_cast<const f32x4*>(&GW[(size_t)(d0 + j) * 8]);
      f32x4 g0 = g[0], g1 = g[1];
      double xd = (double)xv[j];
      lacc[0] += xd * (double)g0[0]; lacc[1] += xd * (double)g0[1];
      lacc[2] += xd * (double)g0[2]; lacc[3] += xd * (double)g0[3];
      lacc[4] += xd * (double)g1[0]; lacc[5] += xd * (double)g1[1];
      lacc[6] += xd * (double)g1[2]; lacc[7] += xd * (double)g1[3];
    }
  }
  #pragma unroll
  for (int e = 0; e < 8; ++e) {
    double v = lacc[e];
    #pragma unroll
    for (int off = 32; off > 0; off >>= 1) v += __shfl_down(v, off);
    lacc[e] = v;
  }
  if (lane == 0) {
    float lg[8];
    #pragma unroll
    for (int e = 0; e < 8; ++e) lg[e] = (float)lacc[e];
    int i0 = 0;
    for (int e = 1; e < 8; ++e) if (lg[e] > lg[i0]) i0 = e;
    int i1 = -1;
    for (int e = 0; e < 8; ++e) {
      if (e == i0) continue;
      if (i1 < 0 || lg[e] > lg[i1]) i1 = e;
    }
    float eb = expf(lg[i1] - lg[i0]);
    float wa = 1.f / (1.f + eb);
    float wb = eb * wa;
    tokE[2 * n] = i0; tokE[2 * n + 1] = i1;
    tokW[2 * n] = wa; tokW[2 * n + 1] = wb;
    atomicAdd(&meta[i0], 1);
    atomicAdd(&meta[i1], 1);
  }
}

// ---------- fused scan (thread 0) + assign (all 256 threads), single block ----------
__global__ __launch_bounds__(256) void scanassign_kernel(const int* __restrict__ tokE,
                                                         const float* __restrict__ tokW,
                                                         int* __restrict__ meta,
                                                         int* __restrict__ map,
                                                         int* __restrict__ list,
                                                         float* __restrict__ wl) {
  if (threadIdx.x == 0) {
    int s = 0, c = 0;
    for (int e = 0; e < 8; ++e) {
      meta[8 + e] = s; meta[16 + e] = s;
      int cnt = meta[e];
      for (int m0 = 0; m0 < cnt; m0 += 128) { map[2 * c] = e; map[2 * c + 1] = m0; ++c; }
      s += cnt;
    }
    for (; c < 80; ++c) map[2 * c] = -1;
  }
  __syncthreads();
  for (int n = threadIdx.x; n < L_SEQ; n += 256) {
    #pragma unroll
    for (int k2 = 0; k2 < 2; ++k2) {
      int e = tokE[2 * n + k2];
      int slot = atomicAdd(&meta[16 + e], 1);
      list[slot] = n;
      wl[slot] = tokW[2 * n + k2];
    }
  }
}

// ============ expert GEMMs (R12 structure): BK=32, 3 LDS buffers, counted vmcnt(4),
// ============ T5 setprio around the MFMA cluster ============
__global__ __launch_bounds__(256) void gemm1p_kernel(const short* __restrict__ Xb,
                                                     const short* __restrict__ W1t,
                                                     const float* __restrict__ B1,
                                                     const int* __restrict__ meta,
                                                     const int* __restrict__ list,
                                                     const int* __restrict__ map,
                                                     short* __restrict__ Hb) {
  const int e = map[2 * blockIdx.x];
  if (e < 0) return;
  const int m0 = map[2 * blockIdx.x + 1];
  const int n0 = blockIdx.y << 7;
  const int cntE = meta[e];
  const int baseE = meta[8 + e];

  __shared__ short As[3][128 * 32];
  __shared__ short Bs[3][128 * 32];

  const int t = threadIdx.x;
  const int l = t & 63;
  const int w = t >> 6;
  const int wm = w >> 1, wn = w & 1;
  const int ln = l & 15, kg = l >> 4;

  size_t asrc[2], bsrc[2];
  #pragma unroll
  for (int c = 0; c < 2; ++c) {
    int idx2 = c * 256 + t;
    int row = idx2 >> 2;
    int sch = (idx2 & 3) ^ ((row >> 2) & 3);
    int idxm = m0 + row; if (idxm > cntE - 1) idxm = cntE - 1;
    int grow = list[baseE + idxm];
    asrc[c] = ((size_t)grow * DMODEL + sch * 8) * 2;
    bsrc[c] = (((size_t)e * NHID + n0 + row) * DMODEL + sch * 8) * 2;
  }

  f32x4 acc[4][4];
  #pragma unroll
  for (int mi = 0; mi < 4; ++mi)
    #pragma unroll
    for (int ni = 0; ni < 4; ++ni) acc[mi][ni] = (f32x4)0.f;

  #define STG1(h_, bf_) do { size_t ko_ = (size_t)(h_) * 64;                        \
    _Pragma("unroll")                                                               \
    for (int c_ = 0; c_ < 2; ++c_) {                                                \
      gload16((const char*)Xb + asrc[c_] + ko_, (char*)As + (bf_) * 8192 + c_ * 4096 + t * 16);  \
      gload16((const char*)W1t + bsrc[c_] + ko_, (char*)Bs + (bf_) * 8192 + c_ * 4096 + t * 16); \
    } } while (0)

  const int H = DMODEL / 32;   // 32
  STG1(0, 0); STG1(1, 1);
  for (int h = 0; h < H; ++h) {
    if (h < H - 1) asm volatile("s_waitcnt vmcnt(4)\ns_barrier" ::: "memory");
    else           asm volatile("s_waitcnt vmcnt(0)\ns_barrier" ::: "memory");
    if (h + 2 < H) STG1(h + 2, (h + 2) % 3);
    const char* ab = (const char*)As + (h % 3) * 8192;
    const char* bb = (const char*)Bs + (h % 3) * 8192;
    s16x8 af[4];
    #pragma unroll
    for (int mi = 0; mi < 4; ++mi) {
      int row = wm * 64 + mi * 16 + ln;
      int cc = kg ^ ((row >> 2) & 3);
      af[mi] = *reinterpret_cast<const s16x8*>(ab + row * 64 + cc * 16);
    }
    __builtin_amdgcn_s_setprio(1);
    #pragma unroll
    for (int ni = 0; ni < 4; ++ni) {
      int col = wn * 64 + ni * 16 + ln;
      int cc = kg ^ ((col >> 2) & 3);
      s16x8 bfr = *reinterpret_cast<const s16x8*>(bb + col * 64 + cc * 16);
      #pragma unroll
      for (int mi = 0; mi < 4; ++mi)
        acc[mi][ni] = __builtin_amdgcn_mfma_f32_16x16x32_bf16(af[mi], bfr, acc[mi][ni], 0, 0, 0);
    }
    __builtin_amdgcn_s_setprio(0);
  }

  #pragma unroll
  for (int mi = 0; mi < 4; ++mi) {
    #pragma unroll
    for (int r = 0; r < 4; ++r) {
      int rl = wm * 64 + mi * 16 + kg * 4 + r;
      if (m0 + rl >= cntE) continue;
      size_t hrow = (size_t)(baseE + m0 + rl) * NHID;
      #pragma unroll
      for (int ni = 0; ni < 4; ++ni) {
        int col = n0 + wn * 64 + ni * 16 + ln;
        float z = acc[mi][ni][r] + B1[e * NHID + col];
        float g = 0.5f * z * (1.f + erff(z * 0.70710678118f));
        Hb[hrow + col] = f2bf(g);
      }
    }
  }
}

__global__ __launch_bounds__(256) void gemm2p_kernel(const short* __restrict__ Hb,
                                                     const short* __restrict__ W2t,
                                                     const float* __restrict__ B2,
                                                     const int* __restrict__ meta,
                                                     const int* __restrict__ list,
                                                     const float* __restrict__ wl,
                                                     const int* __restrict__ map,
                                                     float* __restrict__ out) {
  const int e = map[2 * blockIdx.x];
  if (e < 0) return;
  const int m0 = map[2 * blockIdx.x + 1];
  const int n0 = blockIdx.y << 7;
  const int cntE = meta[e];
  const int baseE = meta[8 + e];

  __shared__ short As[3][128 * 32];
  __shared__ short Bs[3][128 * 32];

  const int t = threadIdx.x;
  const int l = t & 63;
  const int w = t >> 6;
  const int wm = w >> 1, wn = w & 1;
  const int ln = l & 15, kg = l >> 4;

  size_t asrc[2], bsrc[2];
  #pragma unroll
  for (int c = 0; c < 2; ++c) {
    int idx2 = c * 256 + t;
    int row = idx2 >> 2;
    int sch = (idx2 & 3) ^ ((row >> 2) & 3);
    int idxm = m0 + row; if (idxm > cntE - 1) idxm = cntE - 1;
    asrc[c] = (((size_t)(baseE + idxm)) * NHID + sch * 8) * 2;
    bsrc[c] = (((size_t)e * DMODEL + n0 + row) * NHID + sch * 8) * 2;
  }

  f32x4 acc[4][4];
  #pragma unroll
  for (int mi = 0; mi < 4; ++mi)
    #pragma unroll
    for (int ni = 0; ni < 4; ++ni) acc[mi][ni] = (f32x4)0.f;

  #define STG2(h_, bf_) do { size_t ko_ = (size_t)(h_) * 64;                        \
    _Pragma("unroll")                                                               \
    for (int c_ = 0; c_ < 2; ++c_) {                                                \
      gload16((const char*)Hb + asrc[c_] + ko_, (char*)As + (bf_) * 8192 + c_ * 4096 + t * 16);  \
      gload16((const char*)W2t + bsrc[c_] + ko_, (char*)Bs + (bf_) * 8192 + c_ * 4096 + t * 16); \
    } } while (0)

  const int H = NHID / 32;   // 128
  STG2(0, 0); STG2(1, 1);
  for (int h = 0; h < H; ++h) {
    if (h < H - 1) asm volatile("s_waitcnt vmcnt(4)\ns_barrier" ::: "memory");
    else           asm volatile("s_waitcnt vmcnt(0)\ns_barrier" ::: "memory");
    if (h + 2 < H) STG2(h + 2, (h + 2) % 3);
    const char* ab = (const char*)As + (h % 3) * 8192;
    const char* bb = (const char*)Bs + (h % 3) * 8192;
    s16x8 af[4];
    #pragma unroll
    for (int mi = 0; mi < 4; ++mi) {
      int row = wm * 64 + mi * 16 + ln;
      int cc = kg ^ ((row >> 2) & 3);
      af[mi] = *reinterpret_cast<const s16x8*>(ab + row * 64 + cc * 16);
    }
    __builtin_amdgcn_s_setprio(1);
    #pragma unroll
    for (int ni = 0; ni < 4; ++ni) {
      int col = wn * 64 + ni * 16 + ln;
      int cc = kg ^ ((col >> 2) & 3);
      s16x8 bfr = *reinterpret_cast<const s16x8*>(bb + col * 64 + cc * 16);
      #pragma unroll
      for (int mi = 0; mi < 4; ++mi)
        acc[mi][ni] = __builtin_amdgcn_mfma_f32_16x16x32_bf16(af[mi], bfr, acc[mi][ni], 0, 0, 0);
    }
    __builtin_amdgcn_s_setprio(0);
  }

  #pragma unroll
  for (int mi = 0; mi < 4; ++mi) {
    #pragma unroll
    for (int r = 0; r < 4; ++r) {
      int rl = wm * 64 + mi * 16 + kg * 4 + r;
      if (m0 + rl >= cntE) continue;
      int slot = baseE + m0 + rl;
      int token = list[slot];
      float wgt = wl[slot];
      #pragma unroll
      for (int ni = 0; ni < 4; ++ni) {
        int col = n0 + wn * 64 + ni * 16 + ln;
        float z = acc[mi][ni][r] + B2[e * DMODEL + col];
        atomicAdd(&out[(size_t)token * DMODEL + col], wgt * z);
      }
    }
  }
}

extern "C" void kernel_launch(void* const* d_in, const int* in_sizes, int n_in,
                              void* d_out, int out_size, void* d_ws, size_t ws_size,
                              hipStream_t stream) {
  const float* Q  = (const float*)d_in[0];
  const float* K  = (const float*)d_in[1];
  const float* V  = (const float*)d_in[2];
  const float* GW = (const float*)d_in[3];
  const float* W1 = (const float*)d_in[4];
  const float* B1 = (const float*)d_in[5];
  const float* W2 = (const float*)d_in[6];
  const float* B2 = (const float*)d_in[7];
  float* out = (float*)d_out;

  const size_t SPLIT = (size_t)L_SEQ * DMODEL;
  const size_t WT_BYTES = (size_t)NEXP * NHID * DMODEL * 2;
  const size_t SPLIT_REGION = SPLIT * 2 * 9;
  const size_t SMALL = (size_t)L_SEQ * 2 * 4 * 2 + (size_t)NSLOT * 4 * 2 + 4096;
  const size_t PRIMARY_BYTES = WT_BYTES * 2 + SPLIT_REGION + SPLIT * 4 + SPLIT * 2 + SMALL;
  if (ws_size < PRIMARY_BYTES) return;

  char* ws = (char*)d_ws;

  size_t off = 0;
  short* W1t = (short*)(ws + off); off += WT_BYTES;
  short* W2t = (short*)(ws + off); off += WT_BYTES;
  char*  splits = ws + off;        off += SPLIT_REGION;
  short* Qh = (short*)(splits);
  short* Qm = Qh + SPLIT;  short* Ql = Qm + SPLIT;
  short* Kh = Ql + SPLIT;  short* Km = Kh + SPLIT;  short* Kl = Km + SPLIT;
  short* Vth = Kl + SPLIT; short* Vtm = Vth + SPLIT; short* Vtl = Vtm + SPLIT;
  short* Hb = (short*)splits;                       // aliases splits AFTER attn
  float* Xf = (float*)(ws + off);  off += SPLIT * 4;
  short* Xb = (short*)(ws + off);  off += SPLIT * 2; // dedicated (live during attn)
  int*   tokE = (int*)(ws + off);  off += (size_t)L_SEQ * 2 * 4;
  float* tokW = (float*)(ws + off); off += (size_t)L_SEQ * 2 * 4;
  int*   list = (int*)(ws + off);  off += (size_t)NSLOT * 4;
  float* wl = (float*)(ws + off);  off += (size_t)NSLOT * 4;
  int*   meta = (int*)(ws + off);  off += 256;
  int*   map = (int*)(ws + off);   off += 80 * 2 * 4;

  hipMemsetAsync(out, 0, (size_t)out_size * sizeof(float), stream);
  hipMemsetAsync(meta, 0, 256, stream);

  prep_kernel<<<dim3(21504), 256, 0, stream>>>(Q, K, V, W1, W2,
                                               Qh, Qm, Ql, Kh, Km, Kl, Vth, Vtm, Vtl,
                                               W1t, W2t);
  attn_mfma<<<dim3(512), 256, 0, stream>>>(Qh, Qm, Ql, Kh, Km, Kl, Vth, Vtm, Vtl, Xf, Xb);
  gate_kernel<<<dim3(1024), 256, 0, stream>>>(Xf, GW, tokE, tokW, meta);
  scanassign_kernel<<<dim3(1), 256, 0, stream>>>(tokE, tokW, meta, map, list, wl);
  gemm1p_kernel<<<dim3(80, 32), 256, 0, stream>>>(Xb, W1t, B1, meta, list, map, Hb);
  gemm2p_kernel<<<dim3(80, 8), 256, 0, stream>>>(Hb, W2t, B2, meta, list, wl, map, out);
}

// Round 15
// 982.894 us; speedup vs baseline: 1.0107x; 1.0105x over previous
//
#include <hip/hip_runtime.h>
#include <hip/hip_bf16.h>
#include <math.h>

#define L_SEQ 4096
#define DMODEL 1024
#define NHEAD 16
#define HDIM 64
#define NEXP 8
#define NHID 4096
#define NSLOT (L_SEQ * 2)

typedef __attribute__((ext_vector_type(4))) float f32x4;
typedef __attribute__((ext_vector_type(16))) float f32x16;
typedef __attribute__((ext_vector_type(8))) short s16x8;
typedef __attribute__((ext_vector_type(4))) short s16x4;
typedef __attribute__((ext_vector_type(4))) unsigned u32x4;

__device__ __forceinline__ short f2bf(float f) {
  __hip_bfloat16 h = __float2bfloat16(f);
  return *reinterpret_cast<short*>(&h);
}
__device__ __forceinline__ float bf2f(short s) {
  __hip_bfloat16 h;
  *reinterpret_cast<short*>(&h) = s;
  return __bfloat162float(h);
}
__device__ __forceinline__ void split3(float a, short& h, short& m, short& l) {
  h = f2bf(a);
  float r = a - bf2f(h);
  m = f2bf(r);
  float r2 = r - bf2f(m);
  l = f2bf(r2);
}
__device__ __forceinline__ void gload16(const void* g, void* l) {
  __builtin_amdgcn_global_load_lds(
      (const __attribute__((address_space(1))) void*)g,
      (__attribute__((address_space(3))) void*)l, 16, 0, 0);
}

// ---------- fused pre-pass: split Q (blocks 0..2047), split K (2048..4095),
// ---------- V-transpose-split (4096..5119) ----------
__global__ __launch_bounds__(256) void prep_kernel(
    const float* __restrict__ Q, const float* __restrict__ K, const float* __restrict__ V,
    short* __restrict__ Qh, short* __restrict__ Qm, short* __restrict__ Ql,
    short* __restrict__ Kh, short* __restrict__ Km, short* __restrict__ Kl,
    short* __restrict__ Vth, short* __restrict__ Vtm, short* __restrict__ Vtl) {
  __shared__ float Vlds[64][65];
  const int b = blockIdx.x;
  const int t = threadIdx.x;
  if (b < 4096) {
    const bool isQ = (b < 2048);
    const float* src = isQ ? Q : K;
    short* hs = isQ ? Qh : Kh;
    short* ms = isQ ? Qm : Km;
    short* ls = isQ ? Ql : Kl;
    const float scale = isQ ? 0.125f : 1.0f;
    const int nquad = (int)((size_t)L_SEQ * DMODEL / 4);
    int i = (b & 2047) * 256 + t;
    for (; i < nquad; i += 2048 * 256) {
      f32x4 a = reinterpret_cast<const f32x4*>(src)[i];
      a *= scale;
      s16x4 h4, m4, l4;
      #pragma unroll
      for (int j = 0; j < 4; ++j) {
        short h, m, l;
        split3(a[j], h, m, l);
        h4[j] = h; m4[j] = m; l4[j] = l;
      }
      reinterpret_cast<s16x4*>(hs)[i] = h4;
      reinterpret_cast<s16x4*>(ms)[i] = m4;
      reinterpret_cast<s16x4*>(ls)[i] = l4;
    }
  } else {
    const int b2 = b - 4096;
    const int k0 = (b2 & 63) * 64;
    const int head = b2 >> 6;
    {
      int r = t >> 2, c = (t & 3) * 16;
      const f32x4* src = reinterpret_cast<const f32x4*>(&V[(size_t)(k0 + r) * DMODEL + head * HDIM + c]);
      #pragma unroll
      for (int j = 0; j < 4; ++j)
        *reinterpret_cast<f32x4*>(&Vlds[r][c + 4 * j]) = src[j];
    }
    __syncthreads();
    {
      int d = t >> 2, kc = (t & 3) * 16;
      s16x8 h8[2], m8[2], l8[2];
      #pragma unroll
      for (int j = 0; j < 16; ++j) {
        float v = Vlds[kc + j][d];
        short h, m, l;
        split3(v, h, m, l);
        h8[j >> 3][j & 7] = h; m8[j >> 3][j & 7] = m; l8[j >> 3][j & 7] = l;
      }
      size_t base = (size_t)(head * HDIM + d) * L_SEQ + k0 + kc;
      *reinterpret_cast<s16x8*>(&Vth[base]) = h8[0];
      *reinterpret_cast<s16x8*>(&Vth[base + 8]) = h8[1];
      *reinterpret_cast<s16x8*>(&Vtm[base]) = m8[0];
      *reinterpret_cast<s16x8*>(&Vtm[base + 8]) = m8[1];
      *reinterpret_cast<s16x8*>(&Vtl[base]) = l8[0];
      *reinterpret_cast<s16x8*>(&Vtl[base + 8]) = l8[1];
    }
  }
}

// ---------- fused weight transpose: z<8 -> W1 (R=1024,C=4096), z>=8 -> W2 (R=4096,C=1024) ----------
__global__ __launch_bounds__(256) void wtrans_kernel(const float* __restrict__ W1,
                                                     const float* __restrict__ W2,
                                                     short* __restrict__ W1t,
                                                     short* __restrict__ W2t) {
  __shared__ float T[64][65];
  const int f = blockIdx.x;
  const int z = blockIdx.y;
  const float* src;
  short* dst;
  int R, C, r0, c0, e;
  if (z < 8) { e = z; R = DMODEL; C = NHID; src = W1; dst = W1t; r0 = (f >> 6) * 64; c0 = (f & 63) * 64; }
  else { e = z - 8; R = NHID; C = DMODEL; src = W2; dst = W2t; r0 = (f >> 4) * 64; c0 = (f & 15) * 64; }
  const size_t sbase = (size_t)e * R * C;
  const int t = threadIdx.x;
  {
    int rr = t >> 2, cc = (t & 3) * 16;
    #pragma unroll
    for (int j = 0; j < 4; ++j)
      *reinterpret_cast<f32x4*>(&T[rr][cc + 4 * j]) =
          *reinterpret_cast<const f32x4*>(&src[sbase + (size_t)(r0 + rr) * C + c0 + cc + 4 * j]);
  }
  __syncthreads();
  {
    int c = t >> 2, r = (t & 3) * 16;
    s16x8 v0, v1;
    #pragma unroll
    for (int j = 0; j < 8; ++j) { v0[j] = f2bf(T[r + j][c]); v1[j] = f2bf(T[r + 8 + j][c]); }
    size_t dbase = ((size_t)e * C + c0 + c) * R + r0 + r;
    *reinterpret_cast<s16x8*>(&dst[dbase]) = v0;
    *reinterpret_cast<s16x8*>(&dst[dbase + 8]) = v1;
  }
}

// ---------- attention: 32x32x16 MFMA flash, fixed-max softmax, P in registers ----------
__global__ __launch_bounds__(256, 2) void attn_mfma(
    const short* __restrict__ Qh, const short* __restrict__ Qm, const short* __restrict__ Ql,
    const short* __restrict__ Kh, const short* __restrict__ Km, const short* __restrict__ Kl,
    const short* __restrict__ Vth, const short* __restrict__ Vtm, const short* __restrict__ Vtl,
    float* __restrict__ X, short* __restrict__ Xb) {
  __shared__ short Ks[3][64][70];
  __shared__ short Vs[3][64][70];   // transposed: [d][k]
  const int lin = blockIdx.x;                    // 512 blocks
  const int swz = (lin & 7) * 64 + (lin >> 3);   // XCD swizzle (bijective: 512=8*64)
  const int head = swz >> 5;
  const int q0 = (swz & 31) << 7;                // 128-q tile
  const int t = threadIdx.x;
  const int l = t & 63;
  const int wq = t >> 6;
  const int lc = l & 31;
  const int hh = l >> 5;

  const short* Qp[3] = {Qh, Qm, Ql};
  const short* Kp[3] = {Kh, Km, Kl};
  const short* Vp[3] = {Vth, Vtm, Vtl};

  s16x8 qf[3][4];
  {
    size_t qrow = (size_t)(q0 + wq * 32 + lc) * DMODEL + head * HDIM;
    #pragma unroll
    for (int s = 0; s < 3; ++s)
      #pragma unroll
      for (int ds_ = 0; ds_ < 4; ++ds_)
        qf[s][ds_] = *reinterpret_cast<const s16x8*>(&Qp[s][qrow + ds_ * 16 + hh * 8]);
  }

  s16x8 sK[3][2], sV[3][2];
  const int c0 = t * 2;
  const int row0 = c0 >> 3, ch0 = (c0 & 7) * 8;
  const int row1 = (c0 + 1) >> 3, ch1 = ((c0 + 1) & 7) * 8;

  #define LOAD_TILE(k0v)                                                                  \
    _Pragma("unroll")                                                                     \
    for (int s = 0; s < 3; ++s) {                                                         \
      sK[s][0] = *reinterpret_cast<const s16x8*>(&Kp[s][(size_t)((k0v) + row0) * DMODEL + head * HDIM + ch0]); \
      sK[s][1] = *reinterpret_cast<const s16x8*>(&Kp[s][(size_t)((k0v) + row1) * DMODEL + head * HDIM + ch1]); \
      sV[s][0] = *reinterpret_cast<const s16x8*>(&Vp[s][(size_t)(head * HDIM + row0) * L_SEQ + (k0v) + ch0]);  \
      sV[s][1] = *reinterpret_cast<const s16x8*>(&Vp[s][(size_t)(head * HDIM + row1) * L_SEQ + (k0v) + ch1]);  \
    }

  f32x16 acc0 = (f32x16)0.f, acc1 = (f32x16)0.f;
  float l_loc = 0.f;
  const float LOG2E = 1.4426950408889634f;
  const float MBIAS = 46.166241f;

  LOAD_TILE(0);

  for (int kt64 = 0; kt64 < 64; ++kt64) {
    __syncthreads();
    #pragma unroll
    for (int s = 0; s < 3; ++s) {
      *reinterpret_cast<s16x8*>(&Ks[s][row0][ch0]) = sK[s][0];
      *reinterpret_cast<s16x8*>(&Ks[s][row1][ch1]) = sK[s][1];
      *reinterpret_cast<s16x8*>(&Vs[s][row0][ch0]) = sV[s][0];
      *reinterpret_cast<s16x8*>(&Vs[s][row1][ch1]) = sV[s][1];
    }
    __syncthreads();
    if (kt64 < 63) { LOAD_TILE((kt64 + 1) * 64); }

    #pragma unroll
    for (int khalf = 0; khalf < 2; ++khalf) {
      f32x16 st = (f32x16)0.f;
      #pragma unroll
      for (int ds_ = 0; ds_ < 4; ++ds_) {
        s16x8 ah = *reinterpret_cast<const s16x8*>(&Ks[0][khalf * 32 + lc][ds_ * 16 + hh * 8]);
        s16x8 am = *reinterpret_cast<const s16x8*>(&Ks[1][khalf * 32 + lc][ds_ * 16 + hh * 8]);
        s16x8 al = *reinterpret_cast<const s16x8*>(&Ks[2][khalf * 32 + lc][ds_ * 16 + hh * 8]);
        st = __builtin_amdgcn_mfma_f32_32x32x16_bf16(am, qf[1][ds_], st, 0, 0, 0);
        st = __builtin_amdgcn_mfma_f32_32x32x16_bf16(al, qf[0][ds_], st, 0, 0, 0);
        st = __builtin_amdgcn_mfma_f32_32x32x16_bf16(ah, qf[2][ds_], st, 0, 0, 0);
        st = __builtin_amdgcn_mfma_f32_32x32x16_bf16(am, qf[0][ds_], st, 0, 0, 0);
        st = __builtin_amdgcn_mfma_f32_32x32x16_bf16(ah, qf[1][ds_], st, 0, 0, 0);
        st = __builtin_amdgcn_mfma_f32_32x32x16_bf16(ah, qf[0][ds_], st, 0, 0, 0);
      }

      unsigned Eh[4][2], Em[4][2], El[4][2];
      float ps = 0.f;
      #pragma unroll
      for (int q = 0; q < 4; ++q) {
        #pragma unroll
        for (int p = 0; p < 2; ++p) {
          float a = exp2f(fmaf(st[4 * q + 2 * p],     LOG2E, -MBIAS));
          float b = exp2f(fmaf(st[4 * q + 2 * p + 1], LOG2E, -MBIAS));
          ps += a + b;
          unsigned ua = __float_as_uint(a), ub = __float_as_uint(b);
          unsigned ha = ua & 0xffff0000u, hb = ub & 0xffff0000u;
          Eh[q][p] = (ha >> 16) | hb;
          float ra = a - __uint_as_float(ha), rb = b - __uint_as_float(hb);
          unsigned ma = __float_as_uint(ra) & 0xffff0000u, mb = __float_as_uint(rb) & 0xffff0000u;
          Em[q][p] = (ma >> 16) | mb;
          float la = ra - __uint_as_float(ma), lb = rb - __uint_as_float(mb);
          El[q][p] = ((__float_as_uint(la) & 0xffff0000u) >> 16) | (__float_as_uint(lb) & 0xffff0000u);
        }
      }
      l_loc += ps;

      #define EXCH(E, Fout) do { u32x4 f_;                                        \
        _Pragma("unroll") for (int p_ = 0; p_ < 2; ++p_) {                        \
          unsigned sel_ = hh ? E[2 * ks][p_] : E[2 * ks + 1][p_];                 \
          unsigned rc_ = (unsigned)__shfl_xor((int)sel_, 32);                     \
          f_[p_] = hh ? rc_ : E[2 * ks][p_];                                      \
          f_[2 + p_] = hh ? E[2 * ks + 1][p_] : rc_;                              \
        }                                                                         \
        Fout = *reinterpret_cast<s16x8*>(&f_); } while (0)

      #pragma unroll
      for (int ks = 0; ks < 2; ++ks) {
        s16x8 Fh, Fm, Fl;
        EXCH(Eh, Fh);
        EXCH(Em, Fm);
        EXCH(El, Fl);
        const int kcol = khalf * 32 + ks * 16 + hh * 8;
        {
          s16x8 vh = *reinterpret_cast<const s16x8*>(&Vs[0][lc][kcol]);
          s16x8 vm = *reinterpret_cast<const s16x8*>(&Vs[1][lc][kcol]);
          s16x8 vl = *reinterpret_cast<const s16x8*>(&Vs[2][lc][kcol]);
          acc0 = __builtin_amdgcn_mfma_f32_32x32x16_bf16(Fm, vm, acc0, 0, 0, 0);
          acc0 = __builtin_amdgcn_mfma_f32_32x32x16_bf16(Fl, vh, acc0, 0, 0, 0);
          acc0 = __builtin_amdgcn_mfma_f32_32x32x16_bf16(Fh, vl, acc0, 0, 0, 0);
          acc0 = __builtin_amdgcn_mfma_f32_32x32x16_bf16(Fm, vh, acc0, 0, 0, 0);
          acc0 = __builtin_amdgcn_mfma_f32_32x32x16_bf16(Fh, vm, acc0, 0, 0, 0);
          acc0 = __builtin_amdgcn_mfma_f32_32x32x16_bf16(Fh, vh, acc0, 0, 0, 0);
        }
        {
          s16x8 vh = *reinterpret_cast<const s16x8*>(&Vs[0][32 + lc][kcol]);
          s16x8 vm = *reinterpret_cast<const s16x8*>(&Vs[1][32 + lc][kcol]);
          s16x8 vl = *reinterpret_cast<const s16x8*>(&Vs[2][32 + lc][kcol]);
          acc1 = __builtin_amdgcn_mfma_f32_32x32x16_bf16(Fm, vm, acc1, 0, 0, 0);
          acc1 = __builtin_amdgcn_mfma_f32_32x32x16_bf16(Fl, vh, acc1, 0, 0, 0);
          acc1 = __builtin_amdgcn_mfma_f32_32x32x16_bf16(Fh, vl, acc1, 0, 0, 0);
          acc1 = __builtin_amdgcn_mfma_f32_32x32x16_bf16(Fm, vh, acc1, 0, 0, 0);
          acc1 = __builtin_amdgcn_mfma_f32_32x32x16_bf16(Fh, vm, acc1, 0, 0, 0);
          acc1 = __builtin_amdgcn_mfma_f32_32x32x16_bf16(Fh, vh, acc1, 0, 0, 0);
        }
      }
      #undef EXCH
    }
  }

  float l_tot = l_loc + __shfl_xor(l_loc, 32);
  float inv = 1.f / l_tot;
  #pragma unroll
  for (int r = 0; r < 16; ++r) {
    int qrow_ = (r & 3) + 8 * (r >> 2) + 4 * hh;
    float invr = __int_as_float(__builtin_amdgcn_ds_bpermute(qrow_ << 2, __float_as_int(inv)));
    size_t base = (size_t)(q0 + wq * 32 + qrow_) * DMODEL + head * HDIM + lc;
    float o0 = acc0[r] * invr, o1 = acc1[r] * invr;
    X[base] = o0;
    X[base + 32] = o1;
    Xb[base] = f2bf(o0);
    Xb[base + 32] = f2bf(o1);
  }
}

// ---------------- gating: one wave per token, f64 accumulation ----------------
__global__ __launch_bounds__(256) void gate_kernel(const float* __restrict__ X,
                                                   const float* __restrict__ GW,
                                                   int* __restrict__ tokE,
                                                   float* __restrict__ tokW,
                                                   int* __restrict__ meta) {
  const int gid = blockIdx.x * 256 + threadIdx.x;
  const int n = gid >> 6;
  const int lane = threadIdx.x & 63;
  double lacc[8];
  #pragma unroll
  for (int e = 0; e < 8; ++e) lacc[e] = 0.0;
  #pragma unroll
  for (int ch = 0; ch < 4; ++ch) {
    int d0 = ch * 256 + lane * 4;
    f32x4 xv = *reinterpret_cast<const f32x4*>(&X[(size_t)n * DMODEL + d0]);
    #pragma unroll
    for (int j = 0; j < 4; ++j) {
      const f32x4* g = reinterpret_cast<const f32x4*>(&GW[(size_t)(d0 + j) * 8]);
      f32x4 g0 = g[0], g1 = g[1];
      double xd = (double)xv[j];
      lacc[0] += xd * (double)g0[0]; lacc[1] += xd * (double)g0[1];
      lacc[2] += xd * (double)g0[2]; lacc[3] += xd * (double)g0[3];
      lacc[4] += xd * (double)g1[0]; lacc[5] += xd * (double)g1[1];
      lacc[6] += xd * (double)g1[2]; lacc[7] += xd * (double)g1[3];
    }
  }
  #pragma unroll
  for (int e = 0; e < 8; ++e) {
    double v = lacc[e];
    #pragma unroll
    for (int off = 32; off > 0; off >>= 1) v += __shfl_down(v, off);
    lacc[e] = v;
  }
  if (lane == 0) {
    float lg[8];
    #pragma unroll
    for (int e = 0; e < 8; ++e) lg[e] = (float)lacc[e];
    int i0 = 0;
    for (int e = 1; e < 8; ++e) if (lg[e] > lg[i0]) i0 = e;
    int i1 = -1;
    for (int e = 0; e < 8; ++e) {
      if (e == i0) continue;
      if (i1 < 0 || lg[e] > lg[i1]) i1 = e;
    }
    float eb = expf(lg[i1] - lg[i0]);
    float wa = 1.f / (1.f + eb);
    float wb = eb * wa;
    tokE[2 * n] = i0; tokE[2 * n + 1] = i1;
    tokW[2 * n] = wa; tokW[2 * n + 1] = wb;
    atomicAdd(&meta[i0], 1);
    atomicAdd(&meta[i1], 1);
  }
}

// meta: [0..7]=cnt, [8..15]=base, [16..23]=cursor. map: 80x{e,m0} 128-row tiles.
__global__ void scan_kernel(int* meta, int* map) {
  if (threadIdx.x == 0) {
    int s = 0, c = 0;
    for (int e = 0; e < 8; ++e) {
      meta[8 + e] = s; meta[16 + e] = s;
      int cnt = meta[e];
      for (int m0 = 0; m0 < cnt; m0 += 128) { map[2 * c] = e; map[2 * c + 1] = m0; ++c; }
      s += cnt;
    }
    for (; c < 80; ++c) map[2 * c] = -1;
  }
}

__global__ __launch_bounds__(256) void assign_kernel(const int* __restrict__ tokE,
                                                     const float* __restrict__ tokW,
                                                     int* __restrict__ meta,
                                                     int* __restrict__ list,
                                                     float* __restrict__ wl) {
  int n = blockIdx.x * 256 + threadIdx.x;
  if (n >= L_SEQ) return;
  #pragma unroll
  for (int k2 = 0; k2 < 2; ++k2) {
    int e = tokE[2 * n + k2];
    int slot = atomicAdd(&meta[16 + e], 1);
    list[slot] = n;
    wl[slot] = tokW[2 * n + k2];
  }
}

// ============ expert GEMMs (R10 internals): BK=32, 3 LDS buffers, counted vmcnt(4) ============
__global__ __launch_bounds__(256) void gemm1p_kernel(const short* __restrict__ Xb,
                                                     const short* __restrict__ W1t,
                                                     const float* __restrict__ B1,
                                                     const int* __restrict__ meta,
                                                     const int* __restrict__ list,
                                                     const int* __restrict__ map,
                                                     short* __restrict__ Hb) {
  const int e = map[2 * blockIdx.x];
  if (e < 0) return;
  const int m0 = map[2 * blockIdx.x + 1];
  const int n0 = blockIdx.y << 7;
  const int cntE = meta[e];
  const int baseE = meta[8 + e];

  __shared__ short As[3][128 * 32];
  __shared__ short Bs[3][128 * 32];

  const int t = threadIdx.x;
  const int l = t & 63;
  const int w = t >> 6;
  const int wm = w >> 1, wn = w & 1;
  const int ln = l & 15, kg = l >> 4;

  size_t asrc[2], bsrc[2];
  #pragma unroll
  for (int c = 0; c < 2; ++c) {
    int idx2 = c * 256 + t;
    int row = idx2 >> 2;
    int sch = (idx2 & 3) ^ ((row >> 2) & 3);
    int idxm = m0 + row; if (idxm > cntE - 1) idxm = cntE - 1;
    int grow = list[baseE + idxm];
    asrc[c] = ((size_t)grow * DMODEL + sch * 8) * 2;
    bsrc[c] = (((size_t)e * NHID + n0 + row) * DMODEL + sch * 8) * 2;
  }

  f32x4 acc[4][4];
  #pragma unroll
  for (int mi = 0; mi < 4; ++mi)
    #pragma unroll
    for (int ni = 0; ni < 4; ++ni) acc[mi][ni] = (f32x4)0.f;

  #define STG1(h_, bf_) do { size_t ko_ = (size_t)(h_) * 64;                        \
    _Pragma("unroll")                                                               \
    for (int c_ = 0; c_ < 2; ++c_) {                                                \
      gload16((const char*)Xb + asrc[c_] + ko_, (char*)As + (bf_) * 8192 + c_ * 4096 + t * 16);  \
      gload16((const char*)W1t + bsrc[c_] + ko_, (char*)Bs + (bf_) * 8192 + c_ * 4096 + t * 16); \
    } } while (0)

  const int H = DMODEL / 32;   // 32
  STG1(0, 0); STG1(1, 1);
  for (int h = 0; h < H; ++h) {
    if (h < H - 1) asm volatile("s_waitcnt vmcnt(4)\ns_barrier" ::: "memory");
    else           asm volatile("s_waitcnt vmcnt(0)\ns_barrier" ::: "memory");
    if (h + 2 < H) STG1(h + 2, (h + 2) % 3);
    const char* ab = (const char*)As + (h % 3) * 8192;
    const char* bb = (const char*)Bs + (h % 3) * 8192;
    s16x8 af[4];
    #pragma unroll
    for (int mi = 0; mi < 4; ++mi) {
      int row = wm * 64 + mi * 16 + ln;
      int cc = kg ^ ((row >> 2) & 3);
      af[mi] = *reinterpret_cast<const s16x8*>(ab + row * 64 + cc * 16);
    }
    #pragma unroll
    for (int ni = 0; ni < 4; ++ni) {
      int col = wn * 64 + ni * 16 + ln;
      int cc = kg ^ ((col >> 2) & 3);
      s16x8 bfr = *reinterpret_cast<const s16x8*>(bb + col * 64 + cc * 16);
      #pragma unroll
      for (int mi = 0; mi < 4; ++mi)
        acc[mi][ni] = __builtin_amdgcn_mfma_f32_16x16x32_bf16(af[mi], bfr, acc[mi][ni], 0, 0, 0);
    }
  }

  #pragma unroll
  for (int mi = 0; mi < 4; ++mi) {
    #pragma unroll
    for (int r = 0; r < 4; ++r) {
      int rl = wm * 64 + mi * 16 + kg * 4 + r;
      if (m0 + rl >= cntE) continue;
      size_t hrow = (size_t)(baseE + m0 + rl) * NHID;
      #pragma unroll
      for (int ni = 0; ni < 4; ++ni) {
        int col = n0 + wn * 64 + ni * 16 + ln;
        float z = acc[mi][ni][r] + B1[e * NHID + col];
        float g = 0.5f * z * (1.f + erff(z * 0.70710678118f));
        Hb[hrow + col] = f2bf(g);
      }
    }
  }
}

__global__ __launch_bounds__(256) void gemm2p_kernel(const short* __restrict__ Hb,
                                                     const short* __restrict__ W2t,
                                                     const float* __restrict__ B2,
                                                     const int* __restrict__ meta,
                                                     const int* __restrict__ list,
                                                     const float* __restrict__ wl,
                                                     const int* __restrict__ map,
                                                     float* __restrict__ out) {
  const int e = map[2 * blockIdx.x];
  if (e < 0) return;
  const int m0 = map[2 * blockIdx.x + 1];
  const int n0 = blockIdx.y << 7;
  const int cntE = meta[e];
  const int baseE = meta[8 + e];

  __shared__ short As[3][128 * 32];
  __shared__ short Bs[3][128 * 32];

  const int t = threadIdx.x;
  const int l = t & 63;
  const int w = t >> 6;
  const int wm = w >> 1, wn = w & 1;
  const int ln = l & 15, kg = l >> 4;

  size_t asrc[2], bsrc[2];
  #pragma unroll
  for (int c = 0; c < 2; ++c) {
    int idx2 = c * 256 + t;
    int row = idx2 >> 2;
    int sch = (idx2 & 3) ^ ((row >> 2) & 3);
    int idxm = m0 + row; if (idxm > cntE - 1) idxm = cntE - 1;
    asrc[c] = (((size_t)(baseE + idxm)) * NHID + sch * 8) * 2;
    bsrc[c] = (((size_t)e * DMODEL + n0 + row) * NHID + sch * 8) * 2;
  }

  f32x4 acc[4][4];
  #pragma unroll
  for (int mi = 0; mi < 4; ++mi)
    #pragma unroll
    for (int ni = 0; ni < 4; ++ni) acc[mi][ni] = (f32x4)0.f;

  #define STG2(h_, bf_) do { size_t ko_ = (size_t)(h_) * 64;                        \
    _Pragma("unroll")                                                               \
    for (int c_ = 0; c_ < 2; ++c_) {                                                \
      gload16((const char*)Hb + asrc[c_] + ko_, (char*)As + (bf_) * 8192 + c_ * 4096 + t * 16);  \
      gload16((const char*)W2t + bsrc[c_] + ko_, (char*)Bs + (bf_) * 8192 + c_ * 4096 + t * 16); \
    } } while (0)

  const int H = NHID / 32;   // 128
  STG2(0, 0); STG2(1, 1);
  for (int h = 0; h < H; ++h) {
    if (h < H - 1) asm volatile("s_waitcnt vmcnt(4)\ns_barrier" ::: "memory");
    else           asm volatile("s_waitcnt vmcnt(0)\ns_barrier" ::: "memory");
    if (h + 2 < H) STG2(h + 2, (h + 2) % 3);
    const char* ab = (const char*)As + (h % 3) * 8192;
    const char* bb = (const char*)Bs + (h % 3) * 8192;
    s16x8 af[4];
    #pragma unroll
    for (int mi = 0; mi < 4; ++mi) {
      int row = wm * 64 + mi * 16 + ln;
      int cc = kg ^ ((row >> 2) & 3);
      af[mi] = *reinterpret_cast<const s16x8*>(ab + row * 64 + cc * 16);
    }
    #pragma unroll
    for (int ni = 0; ni < 4; ++ni) {
      int col = wn * 64 + ni * 16 + ln;
      int cc = kg ^ ((col >> 2) & 3);
      s16x8 bfr = *reinterpret_cast<const s16x8*>(bb + col * 64 + cc * 16);
      #pragma unroll
      for (int mi = 0; mi < 4; ++mi)
        acc[mi][ni] = __builtin_amdgcn_mfma_f32_16x16x32_bf16(af[mi], bfr, acc[mi][ni], 0, 0, 0);
    }
  }

  #pragma unroll
  for (int mi = 0; mi < 4; ++mi) {
    #pragma unroll
    for (int r = 0; r < 4; ++r) {
      int rl = wm * 64 + mi * 16 + kg * 4 + r;
      if (m0 + rl >= cntE) continue;
      int slot = baseE + m0 + rl;
      int token = list[slot];
      float wgt = wl[slot];
      #pragma unroll
      for (int ni = 0; ni < 4; ++ni) {
        int col = n0 + wn * 64 + ni * 16 + ln;
        float z = acc[mi][ni][r] + B2[e * DMODEL + col];
        atomicAdd(&out[(size_t)token * DMODEL + col], wgt * z);
      }
    }
  }
}

extern "C" void kernel_launch(void* const* d_in, const int* in_sizes, int n_in,
                              void* d_out, int out_size, void* d_ws, size_t ws_size,
                              hipStream_t stream) {
  const float* Q  = (const float*)d_in[0];
  const float* K  = (const float*)d_in[1];
  const float* V  = (const float*)d_in[2];
  const float* GW = (const float*)d_in[3];
  const float* W1 = (const float*)d_in[4];
  const float* B1 = (const float*)d_in[5];
  const float* W2 = (const float*)d_in[6];
  const float* B2 = (const float*)d_in[7];
  float* out = (float*)d_out;

  const size_t SPLIT = (size_t)L_SEQ * DMODEL;
  const size_t WT_BYTES = (size_t)NEXP * NHID * DMODEL * 2;
  const size_t SPLIT_REGION = SPLIT * 2 * 9;
  const size_t SMALL = (size_t)L_SEQ * 2 * 4 * 2 + (size_t)NSLOT * 4 * 2 + 4096;
  const size_t PRIMARY_BYTES = WT_BYTES * 2 + SPLIT_REGION + SPLIT * 4 + SPLIT * 2 + SMALL;
  if (ws_size < PRIMARY_BYTES) return;

  char* ws = (char*)d_ws;

  size_t off = 0;
  short* W1t = (short*)(ws + off); off += WT_BYTES;
  short* W2t = (short*)(ws + off); off += WT_BYTES;
  char*  splits = ws + off;        off += SPLIT_REGION;
  short* Qh = (short*)(splits);
  short* Qm = Qh + SPLIT;  short* Ql = Qm + SPLIT;
  short* Kh = Ql + SPLIT;  short* Km = Kh + SPLIT;  short* Kl = Km + SPLIT;
  short* Vth = Kl + SPLIT; short* Vtm = Vth + SPLIT; short* Vtl = Vtm + SPLIT;
  short* Hb = (short*)splits;                       // aliases splits AFTER attn
  float* Xf = (float*)(ws + off);  off += SPLIT * 4;
  short* Xb = (short*)(ws + off);  off += SPLIT * 2; // dedicated (live during attn)
  int*   tokE = (int*)(ws + off);  off += (size_t)L_SEQ * 2 * 4;
  float* tokW = (float*)(ws + off); off += (size_t)L_SEQ * 2 * 4;
  int*   list = (int*)(ws + off);  off += (size_t)NSLOT * 4;
  float* wl = (float*)(ws + off);  off += (size_t)NSLOT * 4;
  int*   meta = (int*)(ws + off);  off += 256;
  int*   map = (int*)(ws + off);   off += 80 * 2 * 4;

  hipMemsetAsync(out, 0, (size_t)out_size * sizeof(float), stream);
  hipMemsetAsync(meta, 0, 256, stream);

  wtrans_kernel<<<dim3(1024, 16), 256, 0, stream>>>(W1, W2, W1t, W2t);
  prep_kernel<<<dim3(5120), 256, 0, stream>>>(Q, K, V, Qh, Qm, Ql, Kh, Km, Kl, Vth, Vtm, Vtl);
  attn_mfma<<<dim3(512), 256, 0, stream>>>(Qh, Qm, Ql, Kh, Km, Kl, Vth, Vtm, Vtl, Xf, Xb);
  gate_kernel<<<dim3(1024), 256, 0, stream>>>(Xf, GW, tokE, tokW, meta);
  scan_kernel<<<1, 64, 0, stream>>>(meta, map);
  assign_kernel<<<dim3(16), 256, 0, stream>>>(tokE, tokW, meta, list, wl);
  gemm1p_kernel<<<dim3(80, 32), 256, 0, stream>>>(Xb, W1t, B1, meta, list, map, Hb);
  gemm2p_kernel<<<dim3(80, 8), 256, 0, stream>>>(Hb, W2t, B2, meta, list, wl, map, out);
}